// Round 12
// baseline (414.775 us; speedup 1.0000x reference)
//
#include <hip/hip_runtime.h>
#include <math.h>

// ---------------------------------------------------------------------------
// R12: R11's async global_load_lds pipeline, fixed. Root cause of R11 NaN:
// predicated DMA + partial exec => readfirstlane'd LDS base from a non-zero
// first active lane => shifted writes. Fix: features live in a PADDED global
// layout (130x130 px/batch, zero borders, zeroed each launch) so staging is
// an unconditional all-lane DMA copy. Swizzle key = padded column.
// ---------------------------------------------------------------------------

typedef __attribute__((ext_vector_type(8))) short bf16x8;
typedef __attribute__((ext_vector_type(4))) float f32x4;

__device__ inline float bf2f(unsigned short u) {
    unsigned v = ((unsigned)u) << 16;
    return __builtin_bit_cast(float, v);
}
__device__ inline unsigned short f2bf(float f) {
    unsigned u = __builtin_bit_cast(unsigned, f);
    u += 0x7FFF + ((u >> 16) & 1);   // RNE
    return (unsigned short)(u >> 16);
}

#define SWKEY(gx) (((gx) >> 1) & 3)
#define PXB 16900   // 130*130 padded pixels per batch map

// ---- zero the 1-px borders of both padded feature buffers (re-poisoned ws) -
__global__ __launch_bounds__(256) void zero_border(
    unsigned short* __restrict__ fb0, unsigned short* __restrict__ fb1)
{
    int idx = blockIdx.x * 256 + threadIdx.x;   // 2*8*516*16 = 132096
    int u = idx & 15;
    int rest = idx >> 4;
    int bp = rest % 516;
    int rb = rest / 516;
    int b = rb & 7, buf = rb >> 3;
    int p;
    if (bp < 130) p = bp;                              // row 0
    else if (bp < 260) p = 129 * 130 + (bp - 130);     // row 129
    else { int k = bp - 260; int r = (k >> 1) + 1; p = r * 130 + ((k & 1) ? 129 : 0); }
    unsigned short* f = (buf ? fb1 : fb0) + (((size_t)(b * PXB + p)) << 7) + u * 8;
    *(bf16x8*)f = (bf16x8){0, 0, 0, 0, 0, 0, 0, 0};
}

// ---------------- head conv: fp32 NCHW (Cin=3) -> padded NHWC bf16 swizzled -
__global__ __launch_bounds__(256) void head_conv(
    const float* __restrict__ x, const float* __restrict__ w,
    const float* __restrict__ bias, unsigned short* __restrict__ out)
{
    __shared__ float wlds[216];          // [ci][tap][co8]
    __shared__ float tile[3][34 * 34];
    const int tid = threadIdx.x, cog = blockIdx.y, b = blockIdx.z;
    const int tile_y = (blockIdx.x >> 2) * 32, tile_x = (blockIdx.x & 3) * 32;

    if (tid < 216) {
        int co = tid & 7, rest = tid >> 3, tap = rest % 9, ci = rest / 9;
        wlds[tid] = w[((cog * 8 + co) * 3 + ci) * 9 + tap];
    }
    for (int idx = tid; idx < 3 * 34 * 34; idx += 256) {
        int ci = idx / 1156, rem = idx - ci * 1156;
        int r = rem / 34, c = rem - r * 34;
        int gy = tile_y - 1 + r, gx = tile_x - 1 + c;
        float v = 0.f;
        if ((unsigned)gy < 128u && (unsigned)gx < 128u)
            v = x[(((size_t)(b * 3 + ci)) << 14) + (gy << 7) + gx];
        tile[ci][rem] = v;
    }
    __syncthreads();

    const int ty = tid >> 4, tx = tid & 15, py = ty * 2;
    float acc[2][2][8];
    #pragma unroll
    for (int r = 0; r < 2; ++r)
        #pragma unroll
        for (int h = 0; h < 2; ++h)
            #pragma unroll
            for (int co = 0; co < 8; ++co) acc[r][h][co] = 0.f;

    #pragma unroll
    for (int ci = 0; ci < 3; ++ci) {
        #pragma unroll
        for (int ky = 0; ky < 3; ++ky) {
            #pragma unroll
            for (int kx = 0; kx < 3; ++kx) {
                const float* wp = wlds + (ci * 9 + ky * 3 + kx) * 8;
                float i00 = tile[ci][(py + ky) * 34 + tx + kx];
                float i01 = tile[ci][(py + ky) * 34 + tx + 16 + kx];
                float i10 = tile[ci][(py + 1 + ky) * 34 + tx + kx];
                float i11 = tile[ci][(py + 1 + ky) * 34 + tx + 16 + kx];
                #pragma unroll
                for (int co = 0; co < 8; ++co) {
                    float wv = wp[co];
                    acc[0][0][co] += i00 * wv;
                    acc[0][1][co] += i01 * wv;
                    acc[1][0][co] += i10 * wv;
                    acc[1][1][co] += i11 * wv;
                }
            }
        }
    }

    #pragma unroll
    for (int r = 0; r < 2; ++r) {
        #pragma unroll
        for (int h = 0; h < 2; ++h) {
            int gy = tile_y + py + r, gx = tile_x + tx + h * 16;
            bf16x8 pv;
            #pragma unroll
            for (int co = 0; co < 8; ++co)
                pv[co] = (short)f2bf(acc[r][h][co] + bias[cog * 8 + co]);
            int off = (cog >> 2) * 32 + (((cog & 3) ^ SWKEY(gx + 1)) << 3);
            *(bf16x8*)(out + (((size_t)(b * PXB + (gy + 1) * 130 + gx + 1)) << 7) + off) = pv;
        }
    }
}

// ---------------- main conv: implicit GEMM, async-pipelined -----------------
// in: padded swizzled NHWC [8][130*130][128]. K in 4x32-ch quarters, two
// 20.7KB LDS buffers, staged by unconditional global_load_lds width=16.
template <int LM, int NTW, int WNSPLIT, int DOMEAN, int TAILFUSE>
__global__ __launch_bounds__(256, 2) void conv_mfma(
    const unsigned short* __restrict__ in, const unsigned short* __restrict__ wT,
    size_t wstride, const float* __restrict__ bias, unsigned short* __restrict__ out,
    float* __restrict__ meanb, const float* __restrict__ x,
    const unsigned short* __restrict__ kb, float* __restrict__ outf,
    int Coutp, int Cout, int relu)
{
    __shared__ unsigned short lds[TAILFUSE ? 26624 : 20736];
    const int tid = threadIdx.x;
    const int b = blockIdx.y;
    const int row0 = (blockIdx.x >> 3) << 4;   // unpadded tile base
    const int col0 = (blockIdx.x & 7) << 4;
    const int l = tid & 63, wv = tid >> 6;
    const int li = l & 15, lq = l >> 4;
    const int m_base = WNSPLIT ? (wv >> 1) * LM : wv * LM;
    const int n_base = WNSPLIT ? (wv & 1) * NTW : 0;
    const size_t inb = (size_t)b * PXB;
    const unsigned short* wbase = wT + (size_t)b * wstride;

    f32x4 acc[LM][NTW];
    #pragma unroll
    for (int lm = 0; lm < LM; ++lm)
        #pragma unroll
        for (int nt = 0; nt < NTW; ++nt)
            acc[lm][nt] = (f32x4){0.f, 0.f, 0.f, 0.f};

    // stage quarter q (1296 16B units) — unconditional, all lanes active
    auto stage = [&](int q) {
        unsigned short* buf = lds + (q & 1) * 10368;
        #pragma unroll
        for (int i = 0; i < 6; ++i) {
            int u = tid + i * 256;
            if (u < 1296) {
                int px = u >> 2, j = u & 3;
                int hr = px / 18, hc = px - hr * 18;
                const unsigned short* src =
                    in + ((inb + (row0 + hr) * 130 + col0 + hc) << 7) + q * 32 + j * 8;
                __builtin_amdgcn_global_load_lds(
                    (const __attribute__((address_space(1))) void*)src,
                    (__attribute__((address_space(3))) void*)(buf + u * 8),
                    16, 0, 0);
            }
        }
    };

    auto loadB = [&](bf16x8 (&dst)[NTW], int q, int tap) {
        const unsigned short* p = wbase +
            (size_t)(tap * 4 + q) * (Coutp * 32) + (n_base * 16 + li) * 32 + lq * 8;
        #pragma unroll
        for (int nt = 0; nt < NTW; ++nt)
            dst[nt] = *(const bf16x8*)(p + nt * 512);
    };
    auto compute = [&](const unsigned short* buf, bf16x8 (&bf)[NTW], int tap) {
        int ky = tap / 3, kx = tap - ky * 3;
        #pragma unroll
        for (int lm = 0; lm < LM; ++lm) {
            int px = (m_base + lm + ky) * 18 + li + kx;
            int slot = lq ^ SWKEY(col0 + li + kx);   // padded column key
            bf16x8 af = *(const bf16x8*)(buf + px * 32 + slot * 8);
            #pragma unroll
            for (int nt = 0; nt < NTW; ++nt)
                acc[lm][nt] = __builtin_amdgcn_mfma_f32_16x16x32_bf16(
                    af, bf[nt], acc[lm][nt], 0, 0, 0);
        }
    };

    stage(0);
    #pragma unroll 1
    for (int q = 0; q < 4; ++q) {
        __syncthreads();
        const unsigned short* buf = lds + (q & 1) * 10368;
        bf16x8 bA[NTW], bB[NTW];
        loadB(bA, q, 0);
        loadB(bB, q, 1);
        compute(buf, bA, 0);
        loadB(bA, q, 2);
        compute(buf, bB, 1);
        loadB(bB, q, 3);
        compute(buf, bA, 2);
        loadB(bA, q, 4);
        compute(buf, bB, 3);
        loadB(bB, q, 5);
        compute(buf, bA, 4);
        loadB(bA, q, 6);
        compute(buf, bB, 5);
        loadB(bB, q, 7);
        compute(buf, bA, 6);
        loadB(bA, q, 8);
        if (q < 3) stage(q + 1);   // DMA overlaps remaining computes
        compute(buf, bB, 7);
        compute(buf, bA, 8);
    }

    float bv[NTW], msum[NTW];
    #pragma unroll
    for (int nt = 0; nt < NTW; ++nt) {
        int co = (n_base + nt) * 16 + li;
        bv[nt] = (co < Cout) ? bias[co] : 0.f;
        msum[nt] = 0.f;
    }

    if (TAILFUSE) {
        // ---- P (wgt) -> LDS, stride 104 ush; zero pad co 80..95 ----
        __syncthreads();
        #pragma unroll
        for (int lm = 0; lm < LM; ++lm) {
            int rowl = m_base + lm;
            #pragma unroll
            for (int r = 0; r < 4; ++r) {
                int coll = lq * 4 + r;
                #pragma unroll
                for (int nt = 0; nt < NTW; ++nt)
                    lds[(rowl * 16 + coll) * 104 + nt * 16 + li] =
                        f2bf(acc[lm][nt][r] + bv[nt]);
            }
        }
        {
            bf16x8 z = {0, 0, 0, 0, 0, 0, 0, 0};
            *(bf16x8*)(lds + tid * 104 + 80) = z;
            *(bf16x8*)(lds + tid * 104 + 88) = z;
        }
        __syncthreads();

        // ---- e-GEMM: e[px][i] = sum_co P[px][co] * kern[co][i] ----
        f32x4 eacc[4][2];
        #pragma unroll
        for (int mm = 0; mm < 4; ++mm)
            #pragma unroll
            for (int nt = 0; nt < 2; ++nt)
                eacc[mm][nt] = (f32x4){0.f, 0.f, 0.f, 0.f};
        #pragma unroll
        for (int s = 0; s < 3; ++s) {
            bf16x8 kbf[2];
            #pragma unroll
            for (int nt = 0; nt < 2; ++nt)
                kbf[nt] = *(const bf16x8*)(kb + ((s * 2 + nt) * 16 + li) * 32 + lq * 8);
            #pragma unroll
            for (int mm = 0; mm < 4; ++mm) {
                int px = (wv * 4 + mm) * 16 + li;
                bf16x8 pf = *(const bf16x8*)(lds + px * 104 + s * 32 + lq * 8);
                #pragma unroll
                for (int nt = 0; nt < 2; ++nt)
                    eacc[mm][nt] = __builtin_amdgcn_mfma_f32_16x16x32_bf16(
                        pf, kbf[nt], eacc[mm][nt], 0, 0, 0);
            }
        }
        __syncthreads();

        // ---- e (C-layout) -> LDS fp32, stride 33 ----
        float* elds = (float*)lds;
        #pragma unroll
        for (int mm = 0; mm < 4; ++mm) {
            #pragma unroll
            for (int nt = 0; nt < 2; ++nt) {
                int i = nt * 16 + li;
                if (i < 25) {
                    #pragma unroll
                    for (int r = 0; r < 4; ++r) {
                        int px = (wv * 4 + mm) * 16 + lq * 4 + r;
                        elds[px * 33 + i] = eacc[mm][nt][r];
                    }
                }
            }
        }
        __syncthreads();

        // ---- apply ----
        const int h = row0 + (tid >> 4), w = col0 + (tid & 15);
        const int pix = h * 128 + w;
        float e[25];
        #pragma unroll
        for (int i = 0; i < 25; ++i) e[i] = elds[tid * 33 + i];

        int yy[5], xx[5];
        #pragma unroll
        for (int d = 0; d < 5; ++d) {
            int y = h - 2 + d;
            yy[d] = y < 0 ? -y : (y > 127 ? 254 - y : y);
            int xv = w - 2 + d;
            xx[d] = xv < 0 ? -xv : (xv > 127 ? 254 - xv : xv);
        }
        #pragma unroll
        for (int c = 0; c < 3; ++c) {
            const float* xc = x + ((size_t)(b * 3 + c) << 14);
            float s = 0.f;
            #pragma unroll
            for (int dy = 0; dy < 5; ++dy)
                #pragma unroll
                for (int dx = 0; dx < 5; ++dx)
                    s += e[dy * 5 + dx] * xc[yy[dy] * 128 + xx[dx]];
            outf[((size_t)(b * 3 + c) << 14) + pix] = s;
        }
        return;
    }

    #pragma unroll
    for (int lm = 0; lm < LM; ++lm) {
        int row = row0 + m_base + lm;
        #pragma unroll
        for (int r = 0; r < 4; ++r) {
            int col = col0 + lq * 4 + r;
            int key = SWKEY(col + 1);
            size_t pbase = ((size_t)(inb + (row + 1) * 130 + col + 1)) << 7;
            #pragma unroll
            for (int nt = 0; nt < NTW; ++nt) {
                float v = acc[lm][nt][r] + bv[nt];
                if (relu) v = fmaxf(v, 0.f);
                if (DOMEAN) msum[nt] += v;
                int co = (n_base + nt) * 16 + li;
                int off = (co & 96) + ((((co >> 3) & 3) ^ key) << 3) + (co & 7);
                out[pbase + off] = f2bf(v);
            }
        }
    }
    if (DOMEAN) {
        #pragma unroll
        for (int nt = 0; nt < NTW; ++nt) {
            float t = msum[nt];
            t += __shfl_xor(t, 16, 64);
            t += __shfl_xor(t, 32, 64);
            if (lq == 0)
                atomicAdd(&meanb[b * 128 + (n_base + nt) * 16 + li], t);
        }
    }
}

// ---- weight transform: [Co][128][3][3] f32 -> [tap*4+kc][Coutp][32] bf16 ---
__device__ inline void wtrans_one(const float* w, unsigned short* wT,
                                  int Co, int Coutp, int idx)
{
    int ch = idx & 31;
    int rest = idx >> 5;
    int co = rest % Coutp;
    int slice = rest / Coutp;
    int kc = slice & 3, tap = slice >> 2;
    float v = (co < Co) ? w[((size_t)(co * 128 + kc * 32 + ch)) * 9 + tap] : 0.f;
    wT[idx] = f2bf(v);
}

__global__ __launch_bounds__(256) void wtrans6(
    const float* __restrict__ w0, const float* __restrict__ w1,
    const float* __restrict__ w2, const float* __restrict__ w3,
    const float* __restrict__ w4, const float* __restrict__ kern,
    unsigned short* __restrict__ t0, unsigned short* __restrict__ t1,
    unsigned short* __restrict__ t2, unsigned short* __restrict__ t3,
    unsigned short* __restrict__ t4, unsigned short* __restrict__ kb)
{
    int idx = blockIdx.x * 256 + threadIdx.x;
    int y = blockIdx.y;
    if (y < 4) {
        const float* w = y == 0 ? w0 : y == 1 ? w1 : y == 2 ? w2 : w3;
        unsigned short* t = y == 0 ? t0 : y == 1 ? t1 : y == 2 ? t2 : t3;
        wtrans_one(w, t, 128, 128, idx);
    } else if (y == 4) {
        if (idx < 9 * 4 * 80 * 32) wtrans_one(w4, t4, 72, 80, idx);
    } else {
        if (idx < 3072) {
            int lq = (idx & 31) >> 3, j = idx & 7;
            int row = idx >> 5;
            int li = row & 15, snt = row >> 4;
            int s = snt >> 1, nt = snt & 1;
            int co = s * 32 + lq * 8 + j, i = nt * 16 + li;
            float v = (co < 72 && i < 25) ? kern[co * 25 + i] : 0.f;
            kb[idx] = f2bf(v);
        }
    }
}

// ---- SE FC + per-batch scaled weight copy, fused ---------------------------
__global__ __launch_bounds__(256) void wscale8f(
    const unsigned short* __restrict__ wT, const float* __restrict__ meanb,
    const float* __restrict__ w1, const float* __restrict__ b1,
    const float* __restrict__ w2, const float* __restrict__ b2,
    unsigned short* __restrict__ out, int Coutp)
{
    const int b = blockIdx.y, c = threadIdx.x;
    __shared__ float h1[8];
    __shared__ float sl[128];
    if (c < 8) {
        float s = 0.f;
        for (int j = 0; j < 128; ++j) s += w1[c * 128 + j] * meanb[b * 128 + j];
        h1[c] = fmaxf(s * (1.f / 16384.f) + b1[c], 0.f);
    }
    __syncthreads();
    if (c < 128) {
        float s = b2[c];
        #pragma unroll
        for (int j = 0; j < 8; ++j) s += w2[c * 8 + j] * h1[j];
        sl[c] = 1.f / (1.f + expf(-s));
    }
    __syncthreads();
    int r = blockIdx.x * 256 + c;
    int ch = r & 31;
    int kc = ((r >> 5) / Coutp) & 3;
    out[(size_t)b * (9 * 4 * Coutp * 32) + r] = f2bf(bf2f(wT[r]) * sl[kc * 32 + ch]);
}

// ---------------------------------------------------------------------------
extern "C" void kernel_launch(void* const* d_in, const int* in_sizes, int n_in,
                              void* d_out, int out_size, void* d_ws, size_t ws_size,
                              hipStream_t stream)
{
    const float* x      = (const float*)d_in[0];
    const float* w_head = (const float*)d_in[1];
    const float* b_head = (const float*)d_in[2];
    const float* w_h1a  = (const float*)d_in[3];
    const float* b_h1a  = (const float*)d_in[4];
    const float* w_h1b  = (const float*)d_in[5];
    const float* b_h1b  = (const float*)d_in[6];
    const float* du1_w1 = (const float*)d_in[7];
    const float* du1_b1 = (const float*)d_in[8];
    const float* du1_w2 = (const float*)d_in[9];
    const float* du1_b2 = (const float*)d_in[10];
    const float* w_h2a  = (const float*)d_in[11];
    const float* b_h2a  = (const float*)d_in[12];
    const float* w_h2b  = (const float*)d_in[13];
    const float* b_h2b  = (const float*)d_in[14];
    const float* du2_w1 = (const float*)d_in[15];
    const float* du2_b1 = (const float*)d_in[16];
    const float* du2_w2 = (const float*)d_in[17];
    const float* du2_b2 = (const float*)d_in[18];
    const float* w_tail = (const float*)d_in[19];
    const float* b_tail = (const float*)d_in[20];
    const float* kern   = (const float*)d_in[21];
    float* out = (float*)d_out;

    const size_t FBN = (size_t)8 * PXB * 128;            // 17,305,600 elems
    unsigned short* fb0  = (unsigned short*)d_ws;
    unsigned short* fb1  = fb0 + FBN;
    unsigned short* wt1  = fb1 + FBN;                    // 147456 each
    unsigned short* wt2  = wt1 + 147456;
    unsigned short* wt3  = wt2 + 147456;
    unsigned short* wt4  = wt3 + 147456;
    unsigned short* wtt  = wt4 + 147456;                 // 92160
    unsigned short* wsa  = wtt + 92160;                  // 8x scaled h2a weights
    unsigned short* wst  = wsa + 8 * 147456;             // 8x scaled tail weights
    unsigned short* kbb  = wst + 8 * 92160;              // 3072 (kern B-frag)
    float* mean1  = (float*)(kbb + 3072);                // 1024
    float* mean2  = mean1 + 1024;

    dim3 blk(256);
    hipMemsetAsync(mean1, 0, 8192, stream);              // zero mean1+mean2
    zero_border<<<516, blk, 0, stream>>>(fb0, fb1);

    wtrans6<<<dim3(576, 6), blk, 0, stream>>>(w_h1a, w_h1b, w_h2a, w_h2b, w_tail,
                                              kern, wt1, wt2, wt3, wt4, wtt, kbb);

    head_conv<<<dim3(16, 16, 8), blk, 0, stream>>>(x, w_head, b_head, fb0);

    dim3 cgrid(64, 8);   // 512 blocks: 64 tiles/batch x 8 batches
    conv_mfma<8, 4, 1, 0, 0><<<cgrid, blk, 0, stream>>>(
        fb0, wt1, 0, b_h1a, fb1, nullptr, nullptr, nullptr, nullptr, 128, 128, 1);
    conv_mfma<8, 4, 1, 1, 0><<<cgrid, blk, 0, stream>>>(
        fb1, wt2, 0, b_h1b, fb0, mean1, nullptr, nullptr, nullptr, 128, 128, 1);

    wscale8f<<<dim3(576, 8), blk, 0, stream>>>(wt3, mean1, du1_w1, du1_b1,
                                               du1_w2, du1_b2, wsa, 128);

    conv_mfma<8, 4, 1, 0, 0><<<cgrid, blk, 0, stream>>>(
        fb0, wsa, 147456, b_h2a, fb1, nullptr, nullptr, nullptr, nullptr, 128, 128, 1);
    conv_mfma<8, 4, 1, 1, 0><<<cgrid, blk, 0, stream>>>(
        fb1, wt4, 0, b_h2b, fb0, mean2, nullptr, nullptr, nullptr, 128, 128, 1);

    wscale8f<<<dim3(360, 8), blk, 0, stream>>>(wtt, mean2, du2_w1, du2_b1,
                                               du2_w2, du2_b2, wst, 80);

    // tail conv + fused dynamic filter via MFMA e-GEMM (writes final output)
    conv_mfma<4, 5, 0, 0, 1><<<cgrid, blk, 0, stream>>>(
        fb0, wst, 92160, b_tail, nullptr, nullptr, x, kbb, out, 80, 72, 0);
}

// Round 13
// 403.729 us; speedup vs baseline: 1.0274x; 1.0274x over previous
//
#include <hip/hip_runtime.h>
#include <math.h>

// ---------------------------------------------------------------------------
// R13: R12's async DMA pipeline + PLANAR-QUARTER feature layout
// fb[b*4+q][130*130][32ch]: each quarter's staging reads full cache lines
// (R12's interleaved layout fetched 64B/line -> 70MB FETCH, L2 thrash).
// LDS af addressing byte-identical to R12 (measured 0 conflicts).
// ---------------------------------------------------------------------------

typedef __attribute__((ext_vector_type(8))) short bf16x8;
typedef __attribute__((ext_vector_type(4))) float f32x4;

__device__ inline float bf2f(unsigned short u) {
    unsigned v = ((unsigned)u) << 16;
    return __builtin_bit_cast(float, v);
}
__device__ inline unsigned short f2bf(float f) {
    unsigned u = __builtin_bit_cast(unsigned, f);
    u += 0x7FFF + ((u >> 16) & 1);   // RNE
    return (unsigned short)(u >> 16);
}

#define SWKEY(gx) (((gx) >> 1) & 3)
#define PXB 16900   // 130*130 padded pixels per plane

// ---- zero the 1-px borders of all 64 quarter planes (2 buf x 8 b x 4 q) ----
__global__ __launch_bounds__(256) void zero_border(
    unsigned short* __restrict__ fb0, unsigned short* __restrict__ fb1)
{
    int idx = blockIdx.x * 256 + threadIdx.x;   // 2*32*516*4 = 132096
    int u = idx & 3;
    int rest = idx >> 2;
    int bp = rest % 516;
    int pl = rest / 516;                        // 0..63
    int p;
    if (bp < 130) p = bp;                              // row 0
    else if (bp < 260) p = 129 * 130 + (bp - 130);     // row 129
    else { int k = bp - 260; int r = (k >> 1) + 1; p = r * 130 + ((k & 1) ? 129 : 0); }
    unsigned short* f = (pl >= 32 ? fb1 : fb0) +
                        (((size_t)(pl & 31) * PXB + p) << 5) + u * 8;
    *(bf16x8*)f = (bf16x8){0, 0, 0, 0, 0, 0, 0, 0};
}

// ---------------- head conv: fp32 NCHW (Cin=3) -> planar swizzled bf16 ------
__global__ __launch_bounds__(256) void head_conv(
    const float* __restrict__ x, const float* __restrict__ w,
    const float* __restrict__ bias, unsigned short* __restrict__ out)
{
    __shared__ float wlds[216];          // [ci][tap][co8]
    __shared__ float tile[3][34 * 34];
    const int tid = threadIdx.x, cog = blockIdx.y, b = blockIdx.z;
    const int tile_y = (blockIdx.x >> 2) * 32, tile_x = (blockIdx.x & 3) * 32;

    if (tid < 216) {
        int co = tid & 7, rest = tid >> 3, tap = rest % 9, ci = rest / 9;
        wlds[tid] = w[((cog * 8 + co) * 3 + ci) * 9 + tap];
    }
    for (int idx = tid; idx < 3 * 34 * 34; idx += 256) {
        int ci = idx / 1156, rem = idx - ci * 1156;
        int r = rem / 34, c = rem - r * 34;
        int gy = tile_y - 1 + r, gx = tile_x - 1 + c;
        float v = 0.f;
        if ((unsigned)gy < 128u && (unsigned)gx < 128u)
            v = x[(((size_t)(b * 3 + ci)) << 14) + (gy << 7) + gx];
        tile[ci][rem] = v;
    }
    __syncthreads();

    const int ty = tid >> 4, tx = tid & 15, py = ty * 2;
    float acc[2][2][8];
    #pragma unroll
    for (int r = 0; r < 2; ++r)
        #pragma unroll
        for (int h = 0; h < 2; ++h)
            #pragma unroll
            for (int co = 0; co < 8; ++co) acc[r][h][co] = 0.f;

    #pragma unroll
    for (int ci = 0; ci < 3; ++ci) {
        #pragma unroll
        for (int ky = 0; ky < 3; ++ky) {
            #pragma unroll
            for (int kx = 0; kx < 3; ++kx) {
                const float* wp = wlds + (ci * 9 + ky * 3 + kx) * 8;
                float i00 = tile[ci][(py + ky) * 34 + tx + kx];
                float i01 = tile[ci][(py + ky) * 34 + tx + 16 + kx];
                float i10 = tile[ci][(py + 1 + ky) * 34 + tx + kx];
                float i11 = tile[ci][(py + 1 + ky) * 34 + tx + 16 + kx];
                #pragma unroll
                for (int co = 0; co < 8; ++co) {
                    float wv = wp[co];
                    acc[0][0][co] += i00 * wv;
                    acc[0][1][co] += i01 * wv;
                    acc[1][0][co] += i10 * wv;
                    acc[1][1][co] += i11 * wv;
                }
            }
        }
    }

    const int q = cog >> 2, g = cog & 3;
    #pragma unroll
    for (int r = 0; r < 2; ++r) {
        #pragma unroll
        for (int h = 0; h < 2; ++h) {
            int gy = tile_y + py + r, gx = tile_x + tx + h * 16;
            bf16x8 pv;
            #pragma unroll
            for (int co = 0; co < 8; ++co)
                pv[co] = (short)f2bf(acc[r][h][co] + bias[cog * 8 + co]);
            int slot = g ^ SWKEY(gx + 1);
            *(bf16x8*)(out + (((size_t)((b * 4 + q) * PXB + (gy + 1) * 130 + gx + 1)) << 5)
                       + slot * 8) = pv;
        }
    }
}

// ---------------- main conv: implicit GEMM, async-pipelined, planar in ------
template <int LM, int NTW, int WNSPLIT, int DOMEAN, int TAILFUSE>
__global__ __launch_bounds__(256, 2) void conv_mfma(
    const unsigned short* __restrict__ in, const unsigned short* __restrict__ wT,
    size_t wstride, const float* __restrict__ bias, unsigned short* __restrict__ out,
    float* __restrict__ meanb, const float* __restrict__ x,
    const unsigned short* __restrict__ kb, float* __restrict__ outf,
    int Coutp, int Cout, int relu)
{
    __shared__ unsigned short lds[TAILFUSE ? 26624 : 20736];
    const int tid = threadIdx.x;
    const int b = blockIdx.y;
    const int row0 = (blockIdx.x >> 3) << 4;   // unpadded tile base
    const int col0 = (blockIdx.x & 7) << 4;
    const int l = tid & 63, wv = tid >> 6;
    const int li = l & 15, lq = l >> 4;
    const int m_base = WNSPLIT ? (wv >> 1) * LM : wv * LM;
    const int n_base = WNSPLIT ? (wv & 1) * NTW : 0;
    const unsigned short* wbase = wT + (size_t)b * wstride;

    f32x4 acc[LM][NTW];
    #pragma unroll
    for (int lm = 0; lm < LM; ++lm)
        #pragma unroll
        for (int nt = 0; nt < NTW; ++nt)
            acc[lm][nt] = (f32x4){0.f, 0.f, 0.f, 0.f};

    // stage quarter q from its plane (1296 16B units) — all-lane prefix DMA
    auto stage = [&](int q) {
        unsigned short* buf = lds + (q & 1) * 10368;
        const unsigned short* pb = in + (((size_t)(b * 4 + q)) * PXB << 5);
        #pragma unroll
        for (int i = 0; i < 6; ++i) {
            int u = tid + i * 256;
            if (u < 1296) {
                int px = u >> 2, j = u & 3;
                int hr = px / 18, hc = px - hr * 18;
                const unsigned short* src =
                    pb + (((size_t)((row0 + hr) * 130 + col0 + hc)) << 5) + j * 8;
                __builtin_amdgcn_global_load_lds(
                    (const __attribute__((address_space(1))) void*)src,
                    (__attribute__((address_space(3))) void*)(buf + u * 8),
                    16, 0, 0);
            }
        }
    };

    auto loadB = [&](bf16x8 (&dst)[NTW], int q, int tap) {
        const unsigned short* p = wbase +
            (size_t)(tap * 4 + q) * (Coutp * 32) + (n_base * 16 + li) * 32 + lq * 8;
        #pragma unroll
        for (int nt = 0; nt < NTW; ++nt)
            dst[nt] = *(const bf16x8*)(p + nt * 512);
    };
    auto compute = [&](const unsigned short* buf, bf16x8 (&bf)[NTW], int tap) {
        int ky = tap / 3, kx = tap - ky * 3;
        #pragma unroll
        for (int lm = 0; lm < LM; ++lm) {
            int px = (m_base + lm + ky) * 18 + li + kx;
            int slot = lq ^ SWKEY(col0 + li + kx);   // padded column key
            bf16x8 af = *(const bf16x8*)(buf + px * 32 + slot * 8);
            #pragma unroll
            for (int nt = 0; nt < NTW; ++nt)
                acc[lm][nt] = __builtin_amdgcn_mfma_f32_16x16x32_bf16(
                    af, bf[nt], acc[lm][nt], 0, 0, 0);
        }
    };

    stage(0);
    #pragma unroll 1
    for (int q = 0; q < 4; ++q) {
        __syncthreads();
        const unsigned short* buf = lds + (q & 1) * 10368;
        bf16x8 bA[NTW], bB[NTW];
        loadB(bA, q, 0);
        loadB(bB, q, 1);
        compute(buf, bA, 0);
        loadB(bA, q, 2);
        compute(buf, bB, 1);
        loadB(bB, q, 3);
        compute(buf, bA, 2);
        loadB(bA, q, 4);
        compute(buf, bB, 3);
        loadB(bB, q, 5);
        compute(buf, bA, 4);
        loadB(bA, q, 6);
        compute(buf, bB, 5);
        loadB(bB, q, 7);
        compute(buf, bA, 6);
        loadB(bA, q, 8);
        if (q < 3) stage(q + 1);   // DMAs younger than all of q's B loads
        compute(buf, bB, 7);
        compute(buf, bA, 8);
    }

    float bv[NTW], msum[NTW];
    #pragma unroll
    for (int nt = 0; nt < NTW; ++nt) {
        int co = (n_base + nt) * 16 + li;
        bv[nt] = (co < Cout) ? bias[co] : 0.f;
        msum[nt] = 0.f;
    }

    if (TAILFUSE) {
        // ---- P (wgt) -> LDS, stride 104 ush; zero pad co 80..95 ----
        __syncthreads();
        #pragma unroll
        for (int lm = 0; lm < LM; ++lm) {
            int rowl = m_base + lm;
            #pragma unroll
            for (int r = 0; r < 4; ++r) {
                int coll = lq * 4 + r;
                #pragma unroll
                for (int nt = 0; nt < NTW; ++nt)
                    lds[(rowl * 16 + coll) * 104 + nt * 16 + li] =
                        f2bf(acc[lm][nt][r] + bv[nt]);
            }
        }
        {
            bf16x8 z = {0, 0, 0, 0, 0, 0, 0, 0};
            *(bf16x8*)(lds + tid * 104 + 80) = z;
            *(bf16x8*)(lds + tid * 104 + 88) = z;
        }
        __syncthreads();

        // ---- e-GEMM: e[px][i] = sum_co P[px][co] * kern[co][i] ----
        f32x4 eacc[4][2];
        #pragma unroll
        for (int mm = 0; mm < 4; ++mm)
            #pragma unroll
            for (int nt = 0; nt < 2; ++nt)
                eacc[mm][nt] = (f32x4){0.f, 0.f, 0.f, 0.f};
        #pragma unroll
        for (int s = 0; s < 3; ++s) {
            bf16x8 kbf[2];
            #pragma unroll
            for (int nt = 0; nt < 2; ++nt)
                kbf[nt] = *(const bf16x8*)(kb + ((s * 2 + nt) * 16 + li) * 32 + lq * 8);
            #pragma unroll
            for (int mm = 0; mm < 4; ++mm) {
                int px = (wv * 4 + mm) * 16 + li;
                bf16x8 pf = *(const bf16x8*)(lds + px * 104 + s * 32 + lq * 8);
                #pragma unroll
                for (int nt = 0; nt < 2; ++nt)
                    eacc[mm][nt] = __builtin_amdgcn_mfma_f32_16x16x32_bf16(
                        pf, kbf[nt], eacc[mm][nt], 0, 0, 0);
            }
        }
        __syncthreads();

        // ---- e (C-layout) -> LDS fp32, stride 33 ----
        float* elds = (float*)lds;
        #pragma unroll
        for (int mm = 0; mm < 4; ++mm) {
            #pragma unroll
            for (int nt = 0; nt < 2; ++nt) {
                int i = nt * 16 + li;
                if (i < 25) {
                    #pragma unroll
                    for (int r = 0; r < 4; ++r) {
                        int px = (wv * 4 + mm) * 16 + lq * 4 + r;
                        elds[px * 33 + i] = eacc[mm][nt][r];
                    }
                }
            }
        }
        __syncthreads();

        // ---- apply ----
        const int h = row0 + (tid >> 4), w = col0 + (tid & 15);
        const int pix = h * 128 + w;
        float e[25];
        #pragma unroll
        for (int i = 0; i < 25; ++i) e[i] = elds[tid * 33 + i];

        int yy[5], xx[5];
        #pragma unroll
        for (int d = 0; d < 5; ++d) {
            int y = h - 2 + d;
            yy[d] = y < 0 ? -y : (y > 127 ? 254 - y : y);
            int xv = w - 2 + d;
            xx[d] = xv < 0 ? -xv : (xv > 127 ? 254 - xv : xv);
        }
        #pragma unroll
        for (int c = 0; c < 3; ++c) {
            const float* xc = x + ((size_t)(b * 3 + c) << 14);
            float s = 0.f;
            #pragma unroll
            for (int dy = 0; dy < 5; ++dy)
                #pragma unroll
                for (int dx = 0; dx < 5; ++dx)
                    s += e[dy * 5 + dx] * xc[yy[dy] * 128 + xx[dx]];
            outf[((size_t)(b * 3 + c) << 14) + pix] = s;
        }
        return;
    }

    #pragma unroll
    for (int lm = 0; lm < LM; ++lm) {
        int row = row0 + m_base + lm;
        #pragma unroll
        for (int r = 0; r < 4; ++r) {
            int col = col0 + lq * 4 + r;
            int key = SWKEY(col + 1);
            #pragma unroll
            for (int nt = 0; nt < NTW; ++nt) {
                float v = acc[lm][nt][r] + bv[nt];
                if (relu) v = fmaxf(v, 0.f);
                if (DOMEAN) msum[nt] += v;
                int co = (n_base + nt) * 16 + li;
                int q = co >> 5;
                int g = (co >> 3) & 3;
                size_t pbase = ((size_t)((b * 4 + q) * PXB + (row + 1) * 130 + col + 1)) << 5;
                out[pbase + ((g ^ key) << 3) + (co & 7)] = f2bf(v);
            }
        }
    }
    if (DOMEAN) {
        #pragma unroll
        for (int nt = 0; nt < NTW; ++nt) {
            float t = msum[nt];
            t += __shfl_xor(t, 16, 64);
            t += __shfl_xor(t, 32, 64);
            if (lq == 0)
                atomicAdd(&meanb[b * 128 + (n_base + nt) * 16 + li], t);
        }
    }
}

// ---- weight transform: [Co][128][3][3] f32 -> [tap*4+kc][Coutp][32] bf16 ---
__device__ inline void wtrans_one(const float* w, unsigned short* wT,
                                  int Co, int Coutp, int idx)
{
    int ch = idx & 31;
    int rest = idx >> 5;
    int co = rest % Coutp;
    int slice = rest / Coutp;
    int kc = slice & 3, tap = slice >> 2;
    float v = (co < Co) ? w[((size_t)(co * 128 + kc * 32 + ch)) * 9 + tap] : 0.f;
    wT[idx] = f2bf(v);
}

__global__ __launch_bounds__(256) void wtrans6(
    const float* __restrict__ w0, const float* __restrict__ w1,
    const float* __restrict__ w2, const float* __restrict__ w3,
    const float* __restrict__ w4, const float* __restrict__ kern,
    unsigned short* __restrict__ t0, unsigned short* __restrict__ t1,
    unsigned short* __restrict__ t2, unsigned short* __restrict__ t3,
    unsigned short* __restrict__ t4, unsigned short* __restrict__ kb)
{
    int idx = blockIdx.x * 256 + threadIdx.x;
    int y = blockIdx.y;
    if (y < 4) {
        const float* w = y == 0 ? w0 : y == 1 ? w1 : y == 2 ? w2 : w3;
        unsigned short* t = y == 0 ? t0 : y == 1 ? t1 : y == 2 ? t2 : t3;
        wtrans_one(w, t, 128, 128, idx);
    } else if (y == 4) {
        if (idx < 9 * 4 * 80 * 32) wtrans_one(w4, t4, 72, 80, idx);
    } else {
        if (idx < 3072) {
            int lq = (idx & 31) >> 3, j = idx & 7;
            int row = idx >> 5;
            int li = row & 15, snt = row >> 4;
            int s = snt >> 1, nt = snt & 1;
            int co = s * 32 + lq * 8 + j, i = nt * 16 + li;
            float v = (co < 72 && i < 25) ? kern[co * 25 + i] : 0.f;
            kb[idx] = f2bf(v);
        }
    }
}

// ---- SE FC + per-batch scaled weight copy, fused ---------------------------
__global__ __launch_bounds__(256) void wscale8f(
    const unsigned short* __restrict__ wT, const float* __restrict__ meanb,
    const float* __restrict__ w1, const float* __restrict__ b1,
    const float* __restrict__ w2, const float* __restrict__ b2,
    unsigned short* __restrict__ out, int Coutp)
{
    const int b = blockIdx.y, c = threadIdx.x;
    __shared__ float h1[8];
    __shared__ float sl[128];
    if (c < 8) {
        float s = 0.f;
        for (int j = 0; j < 128; ++j) s += w1[c * 128 + j] * meanb[b * 128 + j];
        h1[c] = fmaxf(s * (1.f / 16384.f) + b1[c], 0.f);
    }
    __syncthreads();
    if (c < 128) {
        float s = b2[c];
        #pragma unroll
        for (int j = 0; j < 8; ++j) s += w2[c * 8 + j] * h1[j];
        sl[c] = 1.f / (1.f + expf(-s));
    }
    __syncthreads();
    int r = blockIdx.x * 256 + c;
    int ch = r & 31;
    int kc = ((r >> 5) / Coutp) & 3;
    out[(size_t)b * (9 * 4 * Coutp * 32) + r] = f2bf(bf2f(wT[r]) * sl[kc * 32 + ch]);
}

// ---------------------------------------------------------------------------
extern "C" void kernel_launch(void* const* d_in, const int* in_sizes, int n_in,
                              void* d_out, int out_size, void* d_ws, size_t ws_size,
                              hipStream_t stream)
{
    const float* x      = (const float*)d_in[0];
    const float* w_head = (const float*)d_in[1];
    const float* b_head = (const float*)d_in[2];
    const float* w_h1a  = (const float*)d_in[3];
    const float* b_h1a  = (const float*)d_in[4];
    const float* w_h1b  = (const float*)d_in[5];
    const float* b_h1b  = (const float*)d_in[6];
    const float* du1_w1 = (const float*)d_in[7];
    const float* du1_b1 = (const float*)d_in[8];
    const float* du1_w2 = (const float*)d_in[9];
    const float* du1_b2 = (const float*)d_in[10];
    const float* w_h2a  = (const float*)d_in[11];
    const float* b_h2a  = (const float*)d_in[12];
    const float* w_h2b  = (const float*)d_in[13];
    const float* b_h2b  = (const float*)d_in[14];
    const float* du2_w1 = (const float*)d_in[15];
    const float* du2_b1 = (const float*)d_in[16];
    const float* du2_w2 = (const float*)d_in[17];
    const float* du2_b2 = (const float*)d_in[18];
    const float* w_tail = (const float*)d_in[19];
    const float* b_tail = (const float*)d_in[20];
    const float* kern   = (const float*)d_in[21];
    float* out = (float*)d_out;

    const size_t FBN = (size_t)32 * PXB * 32;            // 17,305,600 elems
    unsigned short* fb0  = (unsigned short*)d_ws;
    unsigned short* fb1  = fb0 + FBN;
    unsigned short* wt1  = fb1 + FBN;                    // 147456 each
    unsigned short* wt2  = wt1 + 147456;
    unsigned short* wt3  = wt2 + 147456;
    unsigned short* wt4  = wt3 + 147456;
    unsigned short* wtt  = wt4 + 147456;                 // 92160
    unsigned short* wsa  = wtt + 92160;                  // 8x scaled h2a weights
    unsigned short* wst  = wsa + 8 * 147456;             // 8x scaled tail weights
    unsigned short* kbb  = wst + 8 * 92160;              // 3072 (kern B-frag)
    float* mean1  = (float*)(kbb + 3072);                // 1024
    float* mean2  = mean1 + 1024;

    dim3 blk(256);
    hipMemsetAsync(mean1, 0, 8192, stream);              // zero mean1+mean2
    zero_border<<<516, blk, 0, stream>>>(fb0, fb1);

    wtrans6<<<dim3(576, 6), blk, 0, stream>>>(w_h1a, w_h1b, w_h2a, w_h2b, w_tail,
                                              kern, wt1, wt2, wt3, wt4, wtt, kbb);

    head_conv<<<dim3(16, 16, 8), blk, 0, stream>>>(x, w_head, b_head, fb0);

    dim3 cgrid(64, 8);   // 512 blocks: 64 tiles/batch x 8 batches
    conv_mfma<8, 4, 1, 0, 0><<<cgrid, blk, 0, stream>>>(
        fb0, wt1, 0, b_h1a, fb1, nullptr, nullptr, nullptr, nullptr, 128, 128, 1);
    conv_mfma<8, 4, 1, 1, 0><<<cgrid, blk, 0, stream>>>(
        fb1, wt2, 0, b_h1b, fb0, mean1, nullptr, nullptr, nullptr, 128, 128, 1);

    wscale8f<<<dim3(576, 8), blk, 0, stream>>>(wt3, mean1, du1_w1, du1_b1,
                                               du1_w2, du1_b2, wsa, 128);

    conv_mfma<8, 4, 1, 0, 0><<<cgrid, blk, 0, stream>>>(
        fb0, wsa, 147456, b_h2a, fb1, nullptr, nullptr, nullptr, nullptr, 128, 128, 1);
    conv_mfma<8, 4, 1, 1, 0><<<cgrid, blk, 0, stream>>>(
        fb1, wt4, 0, b_h2b, fb0, mean2, nullptr, nullptr, nullptr, 128, 128, 1);

    wscale8f<<<dim3(360, 8), blk, 0, stream>>>(wtt, mean2, du2_w1, du2_b1,
                                               du2_w2, du2_b2, wst, 80);

    // tail conv + fused dynamic filter via MFMA e-GEMM (writes final output)
    conv_mfma<4, 5, 0, 0, 1><<<cgrid, blk, 0, stream>>>(
        fb0, wst, 92160, b_tail, nullptr, nullptr, x, kbb, out, 80, 72, 0);
}

// Round 14
// 331.916 us; speedup vs baseline: 1.2496x; 1.2164x over previous
//
#include <hip/hip_runtime.h>
#include <math.h>

// ---------------------------------------------------------------------------
// R14: revert to R10 (best passing config, 341us) after R11-R13's async-DMA
// line was refuted (quarter-split staging breaks fetch or write granularity;
// 5 conv restructures all regressed). Only change vs R10: mean zeroing folded
// into wtrans6 (memset dispatch deleted).
// Convs: 46.3us each = 835 TF = 93% of the 2-barrier K-loop structural
// plateau (~900 TF, m97-class); beyond needs hand-asm (hipBLASLt-style).
// ---------------------------------------------------------------------------

typedef __attribute__((ext_vector_type(8))) short bf16x8;
typedef __attribute__((ext_vector_type(4))) float f32x4;

__device__ inline float bf2f(unsigned short u) {
    unsigned v = ((unsigned)u) << 16;
    return __builtin_bit_cast(float, v);
}
__device__ inline unsigned short f2bf(float f) {
    unsigned u = __builtin_bit_cast(unsigned, f);
    u += 0x7FFF + ((u >> 16) & 1);   // RNE
    return (unsigned short)(u >> 16);
}

// ---------------- head conv: fp32 NCHW (Cin=3) -> NHWC bf16 (C=128) ---------
__global__ __launch_bounds__(256) void head_conv(
    const float* __restrict__ x, const float* __restrict__ w,
    const float* __restrict__ bias, unsigned short* __restrict__ out)
{
    __shared__ float wlds[216];          // [ci][tap][co8]
    __shared__ float tile[3][34 * 34];
    const int tid = threadIdx.x, cog = blockIdx.y, b = blockIdx.z;
    const int tile_y = (blockIdx.x >> 2) * 32, tile_x = (blockIdx.x & 3) * 32;

    if (tid < 216) {
        int co = tid & 7, rest = tid >> 3, tap = rest % 9, ci = rest / 9;
        wlds[tid] = w[((cog * 8 + co) * 3 + ci) * 9 + tap];
    }
    for (int idx = tid; idx < 3 * 34 * 34; idx += 256) {
        int ci = idx / 1156, rem = idx - ci * 1156;
        int r = rem / 34, c = rem - r * 34;
        int gy = tile_y - 1 + r, gx = tile_x - 1 + c;
        float v = 0.f;
        if ((unsigned)gy < 128u && (unsigned)gx < 128u)
            v = x[(((size_t)(b * 3 + ci)) << 14) + (gy << 7) + gx];
        tile[ci][rem] = v;
    }
    __syncthreads();

    const int ty = tid >> 4, tx = tid & 15, py = ty * 2;
    float acc[2][2][8];
    #pragma unroll
    for (int r = 0; r < 2; ++r)
        #pragma unroll
        for (int h = 0; h < 2; ++h)
            #pragma unroll
            for (int co = 0; co < 8; ++co) acc[r][h][co] = 0.f;

    #pragma unroll
    for (int ci = 0; ci < 3; ++ci) {
        #pragma unroll
        for (int ky = 0; ky < 3; ++ky) {
            #pragma unroll
            for (int kx = 0; kx < 3; ++kx) {
                const float* wp = wlds + (ci * 9 + ky * 3 + kx) * 8;
                float i00 = tile[ci][(py + ky) * 34 + tx + kx];
                float i01 = tile[ci][(py + ky) * 34 + tx + 16 + kx];
                float i10 = tile[ci][(py + 1 + ky) * 34 + tx + kx];
                float i11 = tile[ci][(py + 1 + ky) * 34 + tx + 16 + kx];
                #pragma unroll
                for (int co = 0; co < 8; ++co) {
                    float wv = wp[co];
                    acc[0][0][co] += i00 * wv;
                    acc[0][1][co] += i01 * wv;
                    acc[1][0][co] += i10 * wv;
                    acc[1][1][co] += i11 * wv;
                }
            }
        }
    }

    #pragma unroll
    for (int r = 0; r < 2; ++r) {
        #pragma unroll
        for (int h = 0; h < 2; ++h) {
            int gy = tile_y + py + r, gx = tile_x + tx + h * 16;
            bf16x8 pv;
            #pragma unroll
            for (int co = 0; co < 8; ++co)
                pv[co] = (short)f2bf(acc[r][h][co] + bias[cog * 8 + co]);
            *(bf16x8*)(out + (((((size_t)b << 14) + gy * 128 + gx)) << 7) + cog * 8) = pv;
        }
    }
}

// ---------------- main conv: implicit GEMM, bf16 MFMA -----------------------
// Block: 16x16 px tile; A staged in two 64-ch halves, UNPADDED stride 64 ush
// with XOR swizzle (channel-group p = g ^ (px&7)) -> conflict-free b128 reads.
// WNSPLIT=1: 4 waves tile 2 m-groups x 2 n-groups (LM=8, NTW=4 for 128 co).
// DOMEAN: fused SE pooled-sum. TAILFUSE: dynfilter fused (MFMA e-GEMM).
template <int LM, int NTW, int WNSPLIT, int DOMEAN, int TAILFUSE>
__global__ __launch_bounds__(256, 2) void conv_mfma(
    const unsigned short* __restrict__ in, const unsigned short* __restrict__ wT,
    size_t wstride, const float* __restrict__ bias, unsigned short* __restrict__ out,
    float* __restrict__ meanb, const float* __restrict__ x,
    const unsigned short* __restrict__ kb, float* __restrict__ outf,
    int Coutp, int Cout, int relu)
{
    __shared__ unsigned short lds[TAILFUSE ? 26624 : 20736];
    const int tid = threadIdx.x;
    const int b = blockIdx.y;
    const int row0 = (blockIdx.x >> 3) << 4;
    const int col0 = (blockIdx.x & 7) << 4;
    const int l = tid & 63, wv = tid >> 6;
    const int li = l & 15, lq = l >> 4;
    const int m_base = WNSPLIT ? (wv >> 1) * LM : wv * LM;
    const int n_base = WNSPLIT ? (wv & 1) * NTW : 0;
    const size_t inb = ((size_t)b) << 14;
    const unsigned short* wbase = wT + (size_t)b * wstride;

    f32x4 acc[LM][NTW];
    #pragma unroll
    for (int lm = 0; lm < LM; ++lm)
        #pragma unroll
        for (int nt = 0; nt < NTW; ++nt)
            acc[lm][nt] = (f32x4){0.f, 0.f, 0.f, 0.f};

    #pragma unroll 1
    for (int half = 0; half < 2; ++half) {
        __syncthreads();
        for (int u = tid; u < 2592; u += 256) {   // 324 px * 8 ch-groups
            int px = u >> 3, g = u & 7;
            int hr = px / 18, hc = px - hr * 18;
            int gy = row0 - 1 + hr, gx = col0 - 1 + hc;
            bf16x8 v = {0, 0, 0, 0, 0, 0, 0, 0};
            if ((unsigned)gy < 128u && (unsigned)gx < 128u)
                v = *(const bf16x8*)(in + ((inb + (gy << 7) + gx) << 7) + half * 64 + g * 8);
            int p = g ^ (px & 7);                 // XOR swizzle
            *(bf16x8*)(lds + px * 64 + p * 8) = v;
        }
        __syncthreads();

        auto loadB = [&](bf16x8 (&dst)[NTW], int s) {
            int tap = s >> 1, kcl = s & 1;
            const unsigned short* p = wbase +
                (size_t)(tap * 4 + half * 2 + kcl) * (Coutp * 32) +
                (n_base * 16 + li) * 32 + lq * 8;
            #pragma unroll
            for (int nt = 0; nt < NTW; ++nt)
                dst[nt] = *(const bf16x8*)(p + nt * 512);
        };
        auto compute = [&](bf16x8 (&bf)[NTW], int s) {
            int tap = s >> 1, kcl = s & 1;
            int ky = tap / 3, kx = tap - ky * 3;
            int g = kcl * 4 + lq;
            #pragma unroll
            for (int lm = 0; lm < LM; ++lm) {
                int px = (m_base + lm + ky) * 18 + li + kx;
                bf16x8 af = *(const bf16x8*)(lds + px * 64 + ((g ^ (px & 7)) * 8));
                #pragma unroll
                for (int nt = 0; nt < NTW; ++nt)
                    acc[lm][nt] = __builtin_amdgcn_mfma_f32_16x16x32_bf16(
                        af, bf[nt], acc[lm][nt], 0, 0, 0);
            }
        };

        bf16x8 bufA[NTW], bufB[NTW];
        loadB(bufA, 0);
        #pragma unroll 1
        for (int it = 0; it < 18; it += 2) {
            loadB(bufB, it + 1);
            compute(bufA, it);
            if (it + 2 < 18) loadB(bufA, it + 2);
            compute(bufB, it + 1);
        }
    }

    float bv[NTW], msum[NTW];
    #pragma unroll
    for (int nt = 0; nt < NTW; ++nt) {
        int co = (n_base + nt) * 16 + li;
        bv[nt] = (co < Cout) ? bias[co] : 0.f;
        msum[nt] = 0.f;
    }

    if (TAILFUSE) {
        // ---- P (wgt) -> LDS, stride 104 ush; zero pad co 80..95 ----
        __syncthreads();
        #pragma unroll
        for (int lm = 0; lm < LM; ++lm) {
            int rowl = m_base + lm;
            #pragma unroll
            for (int r = 0; r < 4; ++r) {
                int coll = lq * 4 + r;
                #pragma unroll
                for (int nt = 0; nt < NTW; ++nt)
                    lds[(rowl * 16 + coll) * 104 + nt * 16 + li] =
                        f2bf(acc[lm][nt][r] + bv[nt]);
            }
        }
        {
            bf16x8 z = {0, 0, 0, 0, 0, 0, 0, 0};
            *(bf16x8*)(lds + tid * 104 + 80) = z;
            *(bf16x8*)(lds + tid * 104 + 88) = z;
        }
        __syncthreads();

        // ---- e-GEMM: e[px][i] = sum_co P[px][co] * kern[co][i] ----
        f32x4 eacc[4][2];
        #pragma unroll
        for (int mm = 0; mm < 4; ++mm)
            #pragma unroll
            for (int nt = 0; nt < 2; ++nt)
                eacc[mm][nt] = (f32x4){0.f, 0.f, 0.f, 0.f};
        #pragma unroll
        for (int s = 0; s < 3; ++s) {
            bf16x8 kbf[2];
            #pragma unroll
            for (int nt = 0; nt < 2; ++nt)
                kbf[nt] = *(const bf16x8*)(kb + ((s * 2 + nt) * 16 + li) * 32 + lq * 8);
            #pragma unroll
            for (int mm = 0; mm < 4; ++mm) {
                int px = (wv * 4 + mm) * 16 + li;
                bf16x8 pf = *(const bf16x8*)(lds + px * 104 + s * 32 + lq * 8);
                #pragma unroll
                for (int nt = 0; nt < 2; ++nt)
                    eacc[mm][nt] = __builtin_amdgcn_mfma_f32_16x16x32_bf16(
                        pf, kbf[nt], eacc[mm][nt], 0, 0, 0);
            }
        }
        __syncthreads();

        // ---- e (C-layout) -> LDS fp32, stride 33 ----
        float* elds = (float*)lds;
        #pragma unroll
        for (int mm = 0; mm < 4; ++mm) {
            #pragma unroll
            for (int nt = 0; nt < 2; ++nt) {
                int i = nt * 16 + li;
                if (i < 25) {
                    #pragma unroll
                    for (int r = 0; r < 4; ++r) {
                        int px = (wv * 4 + mm) * 16 + lq * 4 + r;
                        elds[px * 33 + i] = eacc[mm][nt][r];
                    }
                }
            }
        }
        __syncthreads();

        // ---- apply ----
        const int h = row0 + (tid >> 4), w = col0 + (tid & 15);
        const int pix = h * 128 + w;
        float e[25];
        #pragma unroll
        for (int i = 0; i < 25; ++i) e[i] = elds[tid * 33 + i];

        int yy[5], xx[5];
        #pragma unroll
        for (int d = 0; d < 5; ++d) {
            int y = h - 2 + d;
            yy[d] = y < 0 ? -y : (y > 127 ? 254 - y : y);
            int xv = w - 2 + d;
            xx[d] = xv < 0 ? -xv : (xv > 127 ? 254 - xv : xv);
        }
        #pragma unroll
        for (int c = 0; c < 3; ++c) {
            const float* xc = x + ((size_t)(b * 3 + c) << 14);
            float s = 0.f;
            #pragma unroll
            for (int dy = 0; dy < 5; ++dy)
                #pragma unroll
                for (int dx = 0; dx < 5; ++dx)
                    s += e[dy * 5 + dx] * xc[yy[dy] * 128 + xx[dx]];
            outf[((size_t)(b * 3 + c) << 14) + pix] = s;
        }
        return;
    }

    #pragma unroll
    for (int lm = 0; lm < LM; ++lm) {
        int row = row0 + m_base + lm;
        #pragma unroll
        for (int r = 0; r < 4; ++r) {
            int col = col0 + lq * 4 + r;
            size_t pbase = (inb + row * 128 + col) * (size_t)Coutp;
            #pragma unroll
            for (int nt = 0; nt < NTW; ++nt) {
                float v = acc[lm][nt][r] + bv[nt];
                if (relu) v = fmaxf(v, 0.f);
                if (DOMEAN) msum[nt] += v;
                out[pbase + (n_base + nt) * 16 + li] = f2bf(v);
            }
        }
    }
    if (DOMEAN) {
        #pragma unroll
        for (int nt = 0; nt < NTW; ++nt) {
            float t = msum[nt];
            t += __shfl_xor(t, 16, 64);
            t += __shfl_xor(t, 32, 64);
            if (lq == 0)
                atomicAdd(&meanb[b * 128 + (n_base + nt) * 16 + li], t);
        }
    }
}

// ---- weight transform: [Co][128][3][3] f32 -> [tap*4+kc][Coutp][32] bf16 ---
__device__ inline void wtrans_one(const float* w, unsigned short* wT,
                                  int Co, int Coutp, int idx)
{
    int ch = idx & 31;
    int rest = idx >> 5;
    int co = rest % Coutp;
    int slice = rest / Coutp;
    int kc = slice & 3, tap = slice >> 2;
    float v = (co < Co) ? w[((size_t)(co * 128 + kc * 32 + ch)) * 9 + tap] : 0.f;
    wT[idx] = f2bf(v);
}

__global__ __launch_bounds__(256) void wtrans6(
    const float* __restrict__ w0, const float* __restrict__ w1,
    const float* __restrict__ w2, const float* __restrict__ w3,
    const float* __restrict__ w4, const float* __restrict__ kern,
    unsigned short* __restrict__ t0, unsigned short* __restrict__ t1,
    unsigned short* __restrict__ t2, unsigned short* __restrict__ t3,
    unsigned short* __restrict__ t4, unsigned short* __restrict__ kb,
    float* __restrict__ meanz)
{
    int idx = blockIdx.x * 256 + threadIdx.x;
    int y = blockIdx.y;
    if (y < 4) {
        const float* w = y == 0 ? w0 : y == 1 ? w1 : y == 2 ? w2 : w3;
        unsigned short* t = y == 0 ? t0 : y == 1 ? t1 : y == 2 ? t2 : t3;
        wtrans_one(w, t, 128, 128, idx);
    } else if (y == 4) {
        if (idx < 9 * 4 * 80 * 32) wtrans_one(w4, t4, 72, 80, idx);
    } else {
        if (idx < 3072) {
            int lq = (idx & 31) >> 3, j = idx & 7;
            int row = idx >> 5;
            int li = row & 15, snt = row >> 4;
            int s = snt >> 1, nt = snt & 1;
            int co = s * 32 + lq * 8 + j, i = nt * 16 + li;
            float v = (co < 72 && i < 25) ? kern[co * 25 + i] : 0.f;
            kb[idx] = f2bf(v);
        }
        if (idx < 2048) meanz[idx] = 0.f;   // zero mean1+mean2 (replaces memset)
    }
}

// ---- SE FC + per-batch scaled weight copy, fused ---------------------------
__global__ __launch_bounds__(256) void wscale8f(
    const unsigned short* __restrict__ wT, const float* __restrict__ meanb,
    const float* __restrict__ w1, const float* __restrict__ b1,
    const float* __restrict__ w2, const float* __restrict__ b2,
    unsigned short* __restrict__ out, int Coutp)
{
    const int b = blockIdx.y, c = threadIdx.x;
    __shared__ float h1[8];
    __shared__ float sl[128];
    if (c < 8) {
        float s = 0.f;
        for (int j = 0; j < 128; ++j) s += w1[c * 128 + j] * meanb[b * 128 + j];
        h1[c] = fmaxf(s * (1.f / 16384.f) + b1[c], 0.f);
    }
    __syncthreads();
    if (c < 128) {
        float s = b2[c];
        #pragma unroll
        for (int j = 0; j < 8; ++j) s += w2[c * 8 + j] * h1[j];
        sl[c] = 1.f / (1.f + expf(-s));
    }
    __syncthreads();
    int r = blockIdx.x * 256 + c;
    int ch = r & 31;
    int kc = ((r >> 5) / Coutp) & 3;
    out[(size_t)b * (9 * 4 * Coutp * 32) + r] = f2bf(bf2f(wT[r]) * sl[kc * 32 + ch]);
}

// ---------------------------------------------------------------------------
extern "C" void kernel_launch(void* const* d_in, const int* in_sizes, int n_in,
                              void* d_out, int out_size, void* d_ws, size_t ws_size,
                              hipStream_t stream)
{
    const float* x      = (const float*)d_in[0];
    const float* w_head = (const float*)d_in[1];
    const float* b_head = (const float*)d_in[2];
    const float* w_h1a  = (const float*)d_in[3];
    const float* b_h1a  = (const float*)d_in[4];
    const float* w_h1b  = (const float*)d_in[5];
    const float* b_h1b  = (const float*)d_in[6];
    const float* du1_w1 = (const float*)d_in[7];
    const float* du1_b1 = (const float*)d_in[8];
    const float* du1_w2 = (const float*)d_in[9];
    const float* du1_b2 = (const float*)d_in[10];
    const float* w_h2a  = (const float*)d_in[11];
    const float* b_h2a  = (const float*)d_in[12];
    const float* w_h2b  = (const float*)d_in[13];
    const float* b_h2b  = (const float*)d_in[14];
    const float* du2_w1 = (const float*)d_in[15];
    const float* du2_b1 = (const float*)d_in[16];
    const float* du2_w2 = (const float*)d_in[17];
    const float* du2_b2 = (const float*)d_in[18];
    const float* w_tail = (const float*)d_in[19];
    const float* b_tail = (const float*)d_in[20];
    const float* kern   = (const float*)d_in[21];
    float* out = (float*)d_out;

    unsigned short* fb0  = (unsigned short*)d_ws;        // 16,777,216 elems
    unsigned short* fb1  = fb0 + 16777216;
    unsigned short* wt1  = fb1 + 16777216;               // 147456 each
    unsigned short* wt2  = wt1 + 147456;
    unsigned short* wt3  = wt2 + 147456;
    unsigned short* wt4  = wt3 + 147456;
    unsigned short* wtt  = wt4 + 147456;                 // 92160
    unsigned short* wsa  = wtt + 92160;                  // 8x scaled h2a weights
    unsigned short* wst  = wsa + 8 * 147456;             // 8x scaled tail weights
    unsigned short* kbb  = wst + 8 * 92160;              // 3072 (kern B-frag)
    float* mean1  = (float*)(kbb + 3072);                // 1024
    float* mean2  = mean1 + 1024;

    dim3 blk(256);
    // wtrans6 also zeroes mean1+mean2 (y==5 branch) — no memset dispatch
    wtrans6<<<dim3(576, 6), blk, 0, stream>>>(w_h1a, w_h1b, w_h2a, w_h2b, w_tail,
                                              kern, wt1, wt2, wt3, wt4, wtt, kbb,
                                              mean1);

    head_conv<<<dim3(16, 16, 8), blk, 0, stream>>>(x, w_head, b_head, fb0);

    dim3 cgrid(64, 8);   // 512 blocks: 64 tiles/batch x 8 batches
    conv_mfma<8, 4, 1, 0, 0><<<cgrid, blk, 0, stream>>>(
        fb0, wt1, 0, b_h1a, fb1, nullptr, nullptr, nullptr, nullptr, 128, 128, 1);
    conv_mfma<8, 4, 1, 1, 0><<<cgrid, blk, 0, stream>>>(
        fb1, wt2, 0, b_h1b, fb0, mean1, nullptr, nullptr, nullptr, 128, 128, 1);

    wscale8f<<<dim3(576, 8), blk, 0, stream>>>(wt3, mean1, du1_w1, du1_b1,
                                               du1_w2, du1_b2, wsa, 128);

    conv_mfma<8, 4, 1, 0, 0><<<cgrid, blk, 0, stream>>>(
        fb0, wsa, 147456, b_h2a, fb1, nullptr, nullptr, nullptr, nullptr, 128, 128, 1);
    conv_mfma<8, 4, 1, 1, 0><<<cgrid, blk, 0, stream>>>(
        fb1, wt4, 0, b_h2b, fb0, mean2, nullptr, nullptr, nullptr, 128, 128, 1);

    wscale8f<<<dim3(360, 8), blk, 0, stream>>>(wtt, mean2, du2_w1, du2_b1,
                                               du2_w2, du2_b2, wst, 80);

    // tail conv + fused dynamic filter via MFMA e-GEMM (writes final output)
    conv_mfma<4, 5, 0, 0, 1><<<cgrid, blk, 0, stream>>>(
        fb0, wst, 92160, b_tail, nullptr, nullptr, x, kbb, out, 80, 72, 0);
}